// Round 2
// baseline (550.729 us; speedup 1.0000x reference)
//
#include <hip/hip_runtime.h>
#include <math.h>

#define S_LEN 2048
#define HIDD  2048
#define NHEAD 16
#define HD    128

// Tiled plane layout for all GEMM operands: plane = [rt][kt][128][32] bf16,
// tile = 8 KB contiguous. rt = row/128 (16 tiles), kt = k/32 (64 tiles).
#define TILE_SH 4096   // shorts per tile

typedef __attribute__((ext_vector_type(8))) short short8;
typedef __attribute__((ext_vector_type(4))) float float4v;
typedef unsigned short ushort_t;

static __device__ __forceinline__ ushort_t f2bf(float f) {
    unsigned int u = __float_as_uint(f);
    u += 0x7fff + ((u >> 16) & 1);
    return (ushort_t)(u >> 16);
}
static __device__ __forceinline__ float bf2f(ushort_t s) {
    return __uint_as_float(((unsigned int)s) << 16);
}
__device__ __forceinline__ float silu_f(float x) { return x / (1.f + expf(-x)); }

__device__ __forceinline__ void gl_lds16(const ushort_t* g, short* l) {
    __builtin_amdgcn_global_load_lds((const __attribute__((address_space(1))) void*)g,
                                     (__attribute__((address_space(3))) void*)l, 16, 0, 0);
}

// fp32 row-major -> (hi, lo) TILED bf16 planes
__global__ __launch_bounds__(256)
void split_kernel(const float* __restrict__ in, ushort_t* __restrict__ hi,
                  ushort_t* __restrict__ lo, int n4)
{
    const int i = blockIdx.x * 256 + threadIdx.x;
    if (i >= n4) return;
    const float4 v = ((const float4*)in)[i];
    ushort4 h, l;
    h.x = f2bf(v.x); l.x = f2bf(v.x - bf2f(h.x));
    h.y = f2bf(v.y); l.y = f2bf(v.y - bf2f(h.y));
    h.z = f2bf(v.z); l.z = f2bf(v.z - bf2f(h.z));
    h.w = f2bf(v.w); l.w = f2bf(v.w - bf2f(h.w));
    const int row = i >> 9, c4 = (i & 511) * 4;      // 512 float4 per 2048-row
    const size_t off = ((size_t)((row >> 7) * 64 + (c4 >> 5))) * TILE_SH
                     + (row & 127) * 32 + (c4 & 31);
    *(ushort4*)&hi[off] = h;
    *(ushort4*)&lo[off] = l;
}

// out += p (final reduction for MODE-1 split-K)
__global__ __launch_bounds__(256)
void addp_kernel(float* __restrict__ out, const float* __restrict__ p, int n4)
{
    const int i = blockIdx.x * 256 + threadIdx.x;
    if (i >= n4) return;
    float4 a = ((const float4*)out)[i];
    const float4 b = ((const float4*)p)[i];
    a.x += b.x; a.y += b.y; a.z += b.z; a.w += b.w;
    ((float4*)out)[i] = a;
}

// W (K x N f32) -> WT hi/lo (N x K bf16), TILED
__global__ __launch_bounds__(256)
void split_transpose(const float* __restrict__ W, ushort_t* __restrict__ Thi,
                     ushort_t* __restrict__ Tlo)
{
    __shared__ float t[64][65];
    const int k0 = blockIdx.y * 64, n0 = blockIdx.x * 64;
    const int tx = threadIdx.x & 15, ty = threadIdx.x >> 4;
    #pragma unroll
    for (int it = 0; it < 4; it++) {
        const int k = ty + it * 16;
        const float4 v = *(const float4*)&W[(size_t)(k0 + k) * HIDD + n0 + tx * 4];
        t[k][tx * 4 + 0] = v.x; t[k][tx * 4 + 1] = v.y;
        t[k][tx * 4 + 2] = v.z; t[k][tx * 4 + 3] = v.w;
    }
    __syncthreads();
    #pragma unroll
    for (int it = 0; it < 4; it++) {
        const int n = ty + it * 16;
        ushort4 h, l; float a;
        a = t[tx * 4 + 0][n]; h.x = f2bf(a); l.x = f2bf(a - bf2f(h.x));
        a = t[tx * 4 + 1][n]; h.y = f2bf(a); l.y = f2bf(a - bf2f(h.y));
        a = t[tx * 4 + 2][n]; h.z = f2bf(a); l.z = f2bf(a - bf2f(h.z));
        a = t[tx * 4 + 3][n]; h.w = f2bf(a); l.w = f2bf(a - bf2f(h.w));
        const int nn_ = n0 + n, kk_ = k0 + tx * 4;
        const size_t off = ((size_t)((nn_ >> 7) * 64 + (kk_ >> 5))) * TILE_SH
                         + (nn_ & 127) * 32 + (kk_ & 31);
        *(ushort4*)&Thi[off] = h;
        *(ushort4*)&Tlo[off] = l;
    }
}

// Split-bf16 MFMA GEMM, 128x128 tile, BK=32, glds staging from TILED planes
// (each glds = 1 KB fully contiguous; LDS image identical to round-4 layout).
// MODE 0: x @ [WqT|WkT|WvT|WgT]; q/k xpos -> bf16 hi/lo [h][s][d]; v -> transposed
//         bf16 hi/lo [h][d][s]; g -> fp32 [s][2048].
// MODE 1: y tiled planes @ WoT -> fp32.  Split-K=2 (grid 512, kh = lin>>8):
//         kh=0 writes outC, kh=1 writes gbuf (carries the partial buffer);
//         addp_kernel sums them. Occupancy fix: 256 blocks was 1 block/CU =
//         1 wave/SIMD -> nothing hides latency (measured 176us for 1/4 the
//         FLOPs of MODE 0). 512 blocks restores 2 waves/SIMD.
template<int MODE>
__global__ __launch_bounds__(256, 2)
void mfma_gemm(const ushort_t* __restrict__ Ahi, const ushort_t* __restrict__ Alo,
               const ushort_t* __restrict__ WT, const int* __restrict__ pos_ids,
               ushort_t* __restrict__ qhi, ushort_t* __restrict__ qlo,
               ushort_t* __restrict__ khi, ushort_t* __restrict__ klo,
               ushort_t* __restrict__ vThi, ushort_t* __restrict__ vTlo,
               float* __restrict__ gbuf, float* __restrict__ outC)
{
    __shared__ __align__(16) short sm[16384];   // 4 planes x 8 KB tile = 32 KB

    const int tid = threadIdx.x;
    const int w = tid >> 6, L = tid & 63;
    const int qd = L >> 4, lc = L & 15;
    const int lin = blockIdx.x;
    int n0, m0, kh = 0;
    if (MODE == 0) {   // XCD-stable n-groups: XCD (lin&7 heuristic) sees n-tiles 8j..8j+7
        n0 = (((lin & 7) << 3) + ((lin >> 3) & 7)) << 7;
        m0 = (lin >> 6) << 7;
    } else {
        n0 = (lin & 15) << 7;
        m0 = ((lin >> 4) & 15) << 7;
        kh = lin >> 8;
    }
    const size_t PL = (size_t)HIDD * HIDD;

    int sel, nn;
    const ushort_t *Bhi, *Blo;
    if (MODE == 0) {
        sel = n0 >> 11; nn = n0 & 2047;
        Bhi = WT + (size_t)sel * 2 * PL; Blo = Bhi + PL;
    } else {
        sel = -1; nn = n0;
        Bhi = WT; Blo = WT + PL;
    }

    // wave w stages plane w: 0:Ahi 1:Alo 2:Bhi 3:Blo
    const ushort_t* pbase = (w == 0) ? Ahi : (w == 1) ? Alo : (w == 2) ? Bhi : Blo;
    const int rt = ((w < 2) ? m0 : nn) >> 7;
    const ushort_t* tb0 = pbase + (size_t)rt * 64 * TILE_SH + L * 8;
    short* ldsw = sm + w * 4096;

    const int wm = (w & 1) * 64, wn = (w >> 1) * 64;
    int aoff[4], boff[4];
    #pragma unroll
    for (int i = 0; i < 4; i++) aoff[i] = (wm + i * 16 + lc) * 32 + qd * 8;
    #pragma unroll
    for (int j = 0; j < 4; j++) boff[j] = (wn + j * 16 + lc) * 32 + qd * 8;

    float4v acc[4][4];
    #pragma unroll
    for (int i = 0; i < 4; i++)
        #pragma unroll
        for (int j = 0; j < 4; j++)
            #pragma unroll
            for (int r = 0; r < 4; r++) acc[i][j][r] = 0.f;

    const int kt0 = (MODE == 1) ? kh * 32 : 0;
    const int kt1 = (MODE == 1) ? kt0 + 32 : 64;
    for (int kt = kt0; kt < kt1; kt++) {
        const ushort_t* g = tb0 + (size_t)kt * TILE_SH;
        #pragma unroll
        for (int t = 0; t < 8; t++)
            gl_lds16(g + t * 512, ldsw + t * 512);
        __syncthreads();

        short8 bhf[4], blf[4];
        #pragma unroll
        for (int j = 0; j < 4; j++) {
            bhf[j] = *(const short8*)(sm + 8192  + boff[j]);
            blf[j] = *(const short8*)(sm + 12288 + boff[j]);
        }
        #pragma unroll
        for (int i = 0; i < 4; i++) {
            const short8 ahf = *(const short8*)(sm + aoff[i]);
            const short8 alf = *(const short8*)(sm + 4096 + aoff[i]);
            #pragma unroll
            for (int j = 0; j < 4; j++) {
                acc[i][j] = __builtin_amdgcn_mfma_f32_16x16x32_bf16(ahf, bhf[j], acc[i][j], 0, 0, 0);
                acc[i][j] = __builtin_amdgcn_mfma_f32_16x16x32_bf16(alf, bhf[j], acc[i][j], 0, 0, 0);
                acc[i][j] = __builtin_amdgcn_mfma_f32_16x16x32_bf16(ahf, blf[j], acc[i][j], 0, 0, 0);
            }
        }
        __syncthreads();
    }

    // ---- epilogue via LDS bounce; stores 16B/lane wave-contiguous.
    float* ob = (float*)sm;              // [32][132]
    const int half = w & 1;
    const int head = nn >> 7;

    // #pragma unroll is REQUIRED here (rule #20): without it, `i` is a runtime
    // index into acc[4][4] -> SROA fails -> the whole 64-float accumulator
    // lives in scratch for the ENTIRE kernel, including the K-loop MFMAs.
    // Evidence: VGPR_Count=64, WRITE_SIZE=3.85 GB/dispatch (scratch writebacks),
    // MfmaUtil 11%. Forcing unroll makes every acc index compile-time constant.
    #pragma unroll
    for (int i = 0; i < 4; i++) {
        #pragma unroll
        for (int j = 0; j < 4; j++)
            #pragma unroll
            for (int r = 0; r < 4; r++)
                ob[(half * 16 + qd * 4 + r) * 132 + wn + j * 16 + lc] = acc[i][j][r];
        __syncthreads();

        if (MODE == 1 || sel == 3) {
            float* dst = (MODE == 1) ? (kh ? gbuf : outC) : gbuf;
            #pragma unroll
            for (int p = 0; p < 4; p++) {
                const int row = p * 8 + (tid >> 5);
                const int c = (tid & 31) * 4;
                const int grow = m0 + (row >> 4) * 64 + i * 16 + (row & 15);
                const float4 vv = *(const float4*)&ob[row * 132 + c];
                *(float4*)&dst[(size_t)grow * HIDD + nn + c] = vv;
            }
        } else if (sel == 2) {
            const int d = tid >> 1, hs = tid & 1;
            const int sbase = m0 + hs * 64 + i * 16;
            short8 h0, h1, l0, l1;
            #pragma unroll
            for (int sp = 0; sp < 8; sp++) {
                float a = ob[(hs * 16 + sp) * 132 + d];
                ushort_t hb = f2bf(a);
                h0[sp] = (short)hb; l0[sp] = (short)f2bf(a - bf2f(hb));
                a = ob[(hs * 16 + 8 + sp) * 132 + d];
                hb = f2bf(a);
                h1[sp] = (short)hb; l1[sp] = (short)f2bf(a - bf2f(hb));
            }
            ushort_t* dh = vThi + ((size_t)head * HD + d) * S_LEN + sbase;
            ushort_t* dl = vTlo + ((size_t)head * HD + d) * S_LEN + sbase;
            *(short8*)dh = h0; *(short8*)(dh + 8) = h1;
            *(short8*)dl = l0; *(short8*)(dl + 8) = l1;
        } else {
            const float sgn = (sel == 0) ? 1.f : -1.f;
            ushort_t* dhb = (sel == 0) ? qhi : khi;
            ushort_t* dlb = (sel == 0) ? qlo : klo;
            #pragma unroll
            for (int p = 0; p < 2; p++) {
                const int row = p * 16 + (tid >> 4);
                const int c8 = (tid & 15) * 8;
                const int grow = m0 + (row >> 4) * 64 + i * 16 + (row & 15);
                const float pos = (float)pos_ids[grow];
                const float pe = sgn * pos * (1.f / 512.f);
                short8 hv, lv;
                #pragma unroll
                for (int pp = 0; pp < 4; pp++) {
                    const int d = c8 + pp * 2;
                    const float v0 = ob[row * 132 + d], v1 = ob[row * 132 + d + 1];
                    const float invf = exp2f(-(float)d * (13.28771238f / 128.f));
                    float s, c_; sincosf(pos * invf, &s, &c_);
                    const float scl = exp2f(log2f(((float)d + 51.2f) * (1.f / 179.2f)) * pe);
                    const float e0 = (v0 * c_ - v1 * s) * scl;
                    const float e1 = (v1 * c_ + v0 * s) * scl;
                    const ushort_t h0 = f2bf(e0), h1 = f2bf(e1);
                    hv[pp * 2] = (short)h0;  hv[pp * 2 + 1] = (short)h1;
                    lv[pp * 2] = (short)f2bf(e0 - bf2f(h0));
                    lv[pp * 2 + 1] = (short)f2bf(e1 - bf2f(h1));
                }
                *(short8*)&dhb[((size_t)head * S_LEN + grow) * HD + c8] = hv;
                *(short8*)&dlb[((size_t)head * S_LEN + grow) * HD + c8] = lv;
            }
        }
        __syncthreads();
    }
}

// Retention: MFMA QK^T -> decay -> P relayout -> MFMA PV -> groupnorm + silu gate
// -> y hi/lo TILED planes.  Block: (head, 64 q-rows), 4 waves.
#define KROW 136
#define VROW 40
#define KH_  0
#define KL_  (32 * KROW)
#define VH_  (2 * 32 * KROW)
#define VL_  (VH_ + 128 * VROW)
#define PH_  (VH_ + 2 * 128 * VROW)
#define PLO_ (PH_ + 64 * VROW)
#define YH_  8704
#define YL_  (YH_ + 64 * KROW)
__global__ __launch_bounds__(256, 2)
void retention2(const ushort_t* __restrict__ qhi, const ushort_t* __restrict__ qlo,
                const ushort_t* __restrict__ khi, const ushort_t* __restrict__ klo,
                const ushort_t* __restrict__ vThi, const ushort_t* __restrict__ vTlo,
                const float* __restrict__ gbuf, const float* __restrict__ gnw,
                const float* __restrict__ gnb,
                ushort_t* __restrict__ yhi, ushort_t* __restrict__ ylo)
{
    __shared__ __align__(16) short sm[26112];

    const int h = blockIdx.y;
    const int qb = (gridDim.x - 1) - blockIdx.x;
    const int r0 = qb * 64;
    const int tid = threadIdx.x;
    const int w = tid >> 6, L = tid & 63;
    const int qd = L >> 4, lc = L & 15;

    const float e = -3.4657359f + (float)h * ((-6.2383246f + 3.4657359f) / 15.f);
    const float lg2g = logf(1.f - expf(e)) * 1.44269504f;

    short8 qfh[4], qfl[4];
    {
        const size_t qb0 = ((size_t)h * S_LEN + r0 + w * 16 + lc) * HD + qd * 8;
        #pragma unroll
        for (int ks = 0; ks < 4; ks++) {
            qfh[ks] = *(const short8*)(qhi + qb0 + ks * 32);
            qfl[ks] = *(const short8*)(qlo + qb0 + ks * 32);
        }
    }

    float4v osum[2][4];
    #pragma unroll
    for (int mt = 0; mt < 2; mt++)
        #pragma unroll
        for (int j = 0; j < 4; j++)
            #pragma unroll
            for (int r = 0; r < 4; r++) osum[mt][j][r] = 0.f;

    const int qh_ = w >> 1, vh_ = w & 1;
    const int nch = (r0 + 64) / 32;

    for (int ch = 0; ch < nch; ch++) {
        const int kg0 = ch * 32;
        #pragma unroll
        for (int t = 0; t < 4; t++) {
            const int c = t * 256 + tid;
            const int p = c >> 9, r = (c >> 4) & 31, qq = c & 15;
            const ushort_t* src = (p ? klo : khi) + ((size_t)h * S_LEN + kg0 + r) * HD + qq * 8;
            *(short8*)(sm + (p ? KL_ : KH_) + r * KROW + qq * 8) = *(const short8*)src;
        }
        #pragma unroll
        for (int t = 0; t < 4; t++) {
            const int c = t * 256 + tid;
            const int p = c >> 9, r = (c >> 2) & 127, qq = c & 3;
            const ushort_t* src = (p ? vTlo : vThi) + ((size_t)h * HD + r) * S_LEN + kg0 + qq * 8;
            *(short8*)(sm + (p ? VL_ : VH_) + r * VROW + qq * 8) = *(const short8*)src;
        }
        __syncthreads();

        float4v sacc[2];
        #pragma unroll
        for (int j = 0; j < 2; j++)
            #pragma unroll
            for (int r = 0; r < 4; r++) sacc[j][r] = 0.f;
        #pragma unroll
        for (int ks = 0; ks < 4; ks++) {
            #pragma unroll
            for (int j = 0; j < 2; j++) {
                const short8 bh = *(const short8*)(sm + KH_ + (j * 16 + lc) * KROW + ks * 32 + qd * 8);
                const short8 bl = *(const short8*)(sm + KL_ + (j * 16 + lc) * KROW + ks * 32 + qd * 8);
                sacc[j] = __builtin_amdgcn_mfma_f32_16x16x32_bf16(qfh[ks], bh, sacc[j], 0, 0, 0);
                sacc[j] = __builtin_amdgcn_mfma_f32_16x16x32_bf16(qfl[ks], bh, sacc[j], 0, 0, 0);
                sacc[j] = __builtin_amdgcn_mfma_f32_16x16x32_bf16(qfh[ks], bl, sacc[j], 0, 0, 0);
            }
        }
        #pragma unroll
        for (int j = 0; j < 2; j++)
            #pragma unroll
            for (int r = 0; r < 4; r++) {
                const int dq = (r0 + w * 16 + qd * 4 + r) - (kg0 + j * 16 + lc);
                const float p = (dq >= 0) ? sacc[j][r] * exp2f(lg2g * (float)dq) : 0.f;
                const ushort_t hb = f2bf(p);
                const int off = (w * 16 + qd * 4 + r) * VROW + j * 16 + lc;
                sm[PH_ + off]  = (short)hb;
                sm[PLO_ + off] = (short)f2bf(p - bf2f(hb));
            }
        __syncthreads();

        #pragma unroll
        for (int mt = 0; mt < 2; mt++) {
            const short8 pfh = *(const short8*)(sm + PH_  + (qh_ * 32 + mt * 16 + lc) * VROW + qd * 8);
            const short8 pfl = *(const short8*)(sm + PLO_ + (qh_ * 32 + mt * 16 + lc) * VROW + qd * 8);
            #pragma unroll
            for (int j = 0; j < 4; j++) {
                const short8 vfh = *(const short8*)(sm + VH_ + (vh_ * 64 + j * 16 + lc) * VROW + qd * 8);
                const short8 vfl = *(const short8*)(sm + VL_ + (vh_ * 64 + j * 16 + lc) * VROW + qd * 8);
                osum[mt][j] = __builtin_amdgcn_mfma_f32_16x16x32_bf16(pfh, vfh, osum[mt][j], 0, 0, 0);
                osum[mt][j] = __builtin_amdgcn_mfma_f32_16x16x32_bf16(pfl, vfh, osum[mt][j], 0, 0, 0);
                osum[mt][j] = __builtin_amdgcn_mfma_f32_16x16x32_bf16(pfh, vfl, osum[mt][j], 0, 0, 0);
            }
        }
        __syncthreads();
    }

    float* fr = (float*)sm;
    #pragma unroll
    for (int mt = 0; mt < 2; mt++)
        #pragma unroll
        for (int r = 0; r < 4; r++) {
            float s1 = 0.f, s2 = 0.f;
            #pragma unroll
            for (int j = 0; j < 4; j++) { const float v = osum[mt][j][r]; s1 += v; s2 += v * v; }
            const int row = qh_ * 32 + mt * 16 + qd * 4 + r;
            fr[row * 32 + vh_ * 16 + lc] = s1;
            fr[2048 + row * 32 + vh_ * 16 + lc] = s2;
        }
    __syncthreads();
    if (tid < 64) {
        float s1 = 0.f, s2 = 0.f;
        #pragma unroll
        for (int t = 0; t < 32; t++) { s1 += fr[tid * 32 + t]; s2 += fr[2048 + tid * 32 + t]; }
        const float mean = s1 * (1.f / 128.f);
        const float var  = s2 * (1.f / 128.f) - mean * mean;
        fr[4096 + tid] = mean;
        fr[4160 + tid] = 1.f / sqrtf(var + 1e-5f);
    }
    __syncthreads();

    #pragma unroll
    for (int mt = 0; mt < 2; mt++)
        #pragma unroll
        for (int r = 0; r < 4; r++) {
            const int row = qh_ * 32 + mt * 16 + qd * 4 + r;
            const float mean = fr[4096 + row], inv = fr[4160 + row];
            const int grow = r0 + row;
            #pragma unroll
            for (int j = 0; j < 4; j++) {
                const int col = vh_ * 64 + j * 16 + lc;
                const float gv = gbuf[(size_t)grow * HIDD + h * HD + col];
                const float o = ((osum[mt][j][r] - mean) * inv * gnw[h * HD + col]
                                 + gnb[h * HD + col]) * silu_f(gv);
                const ushort_t hb = f2bf(o);
                sm[YH_ + row * KROW + col] = (short)hb;
                sm[YL_ + row * KROW + col] = (short)f2bf(o - bf2f(hb));
            }
        }
    __syncthreads();
    {
        // y -> TILED planes: row = r0+r_, col = h*128 + (tid&3)*32 + c8*8
        const int r_ = tid >> 2, cs = (tid & 3) * 32;
        const int grow = r0 + r_;
        const size_t tb = ((size_t)((grow >> 7) * 64 + h * 4 + (tid & 3))) * TILE_SH
                        + (grow & 127) * 32;
        #pragma unroll
        for (int c8 = 0; c8 < 4; c8++) {
            *(short8*)(yhi + tb + c8 * 8) = *(const short8*)(sm + YH_ + r_ * KROW + cs + c8 * 8);
            *(short8*)(ylo + tb + c8 * 8) = *(const short8*)(sm + YL_ + r_ * KROW + cs + c8 * 8);
        }
    }
}

extern "C" void kernel_launch(void* const* d_in, const int* in_sizes, int n_in,
                              void* d_out, int out_size, void* d_ws, size_t ws_size,
                              hipStream_t stream) {
    const float* x   = (const float*)d_in[0];
    const int*   pid = (const int*)d_in[1];
    const float* W[5] = {(const float*)d_in[2], (const float*)d_in[3], (const float*)d_in[4],
                         (const float*)d_in[5], (const float*)d_in[6]};
    const float* gnw = (const float*)d_in[7];
    const float* gnb = (const float*)d_in[8];
    float* out = (float*)d_out;
    (void)in_sizes; (void)n_in; (void)out_size; (void)ws_size;

    const size_t PL = (size_t)HIDD * HIDD;

    ushort_t* wt   = (ushort_t*)d_ws;          // 10 tiled planes = 80 MiB
    ushort_t* xhi  = wt + 10 * PL;             // tiled
    ushort_t* xlo  = xhi + PL;
    ushort_t* qhi_ = xlo + PL;                 // row-major [h][s][d]
    ushort_t* qlo_ = qhi_ + PL;
    ushort_t* khi_ = qlo_ + PL;
    ushort_t* klo_ = khi_ + PL;
    ushort_t* vThi = klo_ + PL;                // row-major [h][d][s]
    ushort_t* vTlo = vThi + PL;
    float*    gbuf = (float*)(vTlo + PL);      // row-major fp32
    ushort_t* yhi  = (ushort_t*)(gbuf + PL);   // tiled
    ushort_t* ylo  = yhi + PL;
    // MODE-1 split-K partial: reuse the x planes (dead after mfma_gemm<0>).
    float*    p1   = (float*)xhi;              // PL floats = 16 MiB = xhi+xlo

    split_kernel<<<(int)(PL / 4 / 256), 256, 0, stream>>>(x, xhi, xlo, (int)(PL / 4));
    for (int m = 0; m < 5; m++)
        split_transpose<<<dim3(32, 32), 256, 0, stream>>>(W[m], wt + (size_t)m * 2 * PL,
                                                          wt + (size_t)m * 2 * PL + PL);

    mfma_gemm<0><<<1024, 256, 0, stream>>>(xhi, xlo, wt, pid,
        qhi_, qlo_, khi_, klo_, vThi, vTlo, gbuf, nullptr);

    retention2<<<dim3(32, 16), 256, 0, stream>>>(qhi_, qlo_, khi_, klo_, vThi, vTlo,
        gbuf, gnw, gnb, yhi, ylo);

    mfma_gemm<1><<<512, 256, 0, stream>>>(yhi, ylo, wt + 8 * PL, pid,
        nullptr, nullptr, nullptr, nullptr, nullptr, nullptr, p1, out);

    addp_kernel<<<(int)(PL / 4 / 256), 256, 0, stream>>>(out, p1, (int)(PL / 4));
}

// Round 3
// 535.538 us; speedup vs baseline: 1.0284x; 1.0284x over previous
//
#include <hip/hip_runtime.h>
#include <math.h>

#define S_LEN 2048
#define HIDD  2048
#define NHEAD 16
#define HD    128

// Tiled plane layout for all GEMM operands: plane = [rt][kt][128][32] bf16,
// tile = 8 KB contiguous. rt = row/128 (16 tiles), kt = k/32 (64 tiles).
#define TILE_SH 4096   // shorts per tile

typedef __attribute__((ext_vector_type(8))) short short8;
typedef __attribute__((ext_vector_type(4))) float float4v;
typedef unsigned short ushort_t;

static __device__ __forceinline__ ushort_t f2bf(float f) {
    unsigned int u = __float_as_uint(f);
    u += 0x7fff + ((u >> 16) & 1);
    return (ushort_t)(u >> 16);
}
static __device__ __forceinline__ float bf2f(ushort_t s) {
    return __uint_as_float(((unsigned int)s) << 16);
}
__device__ __forceinline__ float silu_f(float x) { return x / (1.f + expf(-x)); }

__device__ __forceinline__ void gl_lds16(const ushort_t* g, short* l) {
    __builtin_amdgcn_global_load_lds((const __attribute__((address_space(1))) void*)g,
                                     (__attribute__((address_space(3))) void*)l, 16, 0, 0);
}

// fp32 row-major -> (hi, lo) TILED bf16 planes
__global__ __launch_bounds__(256)
void split_kernel(const float* __restrict__ in, ushort_t* __restrict__ hi,
                  ushort_t* __restrict__ lo, int n4)
{
    const int i = blockIdx.x * 256 + threadIdx.x;
    if (i >= n4) return;
    const float4 v = ((const float4*)in)[i];
    ushort4 h, l;
    h.x = f2bf(v.x); l.x = f2bf(v.x - bf2f(h.x));
    h.y = f2bf(v.y); l.y = f2bf(v.y - bf2f(h.y));
    h.z = f2bf(v.z); l.z = f2bf(v.z - bf2f(h.z));
    h.w = f2bf(v.w); l.w = f2bf(v.w - bf2f(h.w));
    const int row = i >> 9, c4 = (i & 511) * 4;      // 512 float4 per 2048-row
    const size_t off = ((size_t)((row >> 7) * 64 + (c4 >> 5))) * TILE_SH
                     + (row & 127) * 32 + (c4 & 31);
    *(ushort4*)&hi[off] = h;
    *(ushort4*)&lo[off] = l;
}

// out += p (final reduction for MODE-1 split-K)
__global__ __launch_bounds__(256)
void addp_kernel(float* __restrict__ out, const float* __restrict__ p, int n4)
{
    const int i = blockIdx.x * 256 + threadIdx.x;
    if (i >= n4) return;
    float4 a = ((const float4*)out)[i];
    const float4 b = ((const float4*)p)[i];
    a.x += b.x; a.y += b.y; a.z += b.z; a.w += b.w;
    ((float4*)out)[i] = a;
}

// W (K x N f32) -> WT hi/lo (N x K bf16), TILED
__global__ __launch_bounds__(256)
void split_transpose(const float* __restrict__ W, ushort_t* __restrict__ Thi,
                     ushort_t* __restrict__ Tlo)
{
    __shared__ float t[64][65];
    const int k0 = blockIdx.y * 64, n0 = blockIdx.x * 64;
    const int tx = threadIdx.x & 15, ty = threadIdx.x >> 4;
    #pragma unroll
    for (int it = 0; it < 4; it++) {
        const int k = ty + it * 16;
        const float4 v = *(const float4*)&W[(size_t)(k0 + k) * HIDD + n0 + tx * 4];
        t[k][tx * 4 + 0] = v.x; t[k][tx * 4 + 1] = v.y;
        t[k][tx * 4 + 2] = v.z; t[k][tx * 4 + 3] = v.w;
    }
    __syncthreads();
    #pragma unroll
    for (int it = 0; it < 4; it++) {
        const int n = ty + it * 16;
        ushort4 h, l; float a;
        a = t[tx * 4 + 0][n]; h.x = f2bf(a); l.x = f2bf(a - bf2f(h.x));
        a = t[tx * 4 + 1][n]; h.y = f2bf(a); l.y = f2bf(a - bf2f(h.y));
        a = t[tx * 4 + 2][n]; h.z = f2bf(a); l.z = f2bf(a - bf2f(h.z));
        a = t[tx * 4 + 3][n]; h.w = f2bf(a); l.w = f2bf(a - bf2f(h.w));
        const int nn_ = n0 + n, kk_ = k0 + tx * 4;
        const size_t off = ((size_t)((nn_ >> 7) * 64 + (kk_ >> 5))) * TILE_SH
                         + (nn_ & 127) * 32 + (kk_ & 31);
        *(ushort4*)&Thi[off] = h;
        *(ushort4*)&Tlo[off] = l;
    }
}

// Split-bf16 MFMA GEMM, 128x128 tile, BK=32.
// Round-3 structure: double-buffered LDS (2 x 32 KB) + stage-ahead.
//   prologue: stage(buf0, kt0); vmcnt(0); barrier
//   iter kt : stage(buf^1, kt+1); compute(buf); vmcnt(0); barrier; flip
// One barrier per K-step (was two), and the global_load_lds latency hides
// under the MFMA/ds_read phase (T3 minimum-2-phase recipe).
// LDS bank-conflict fix (T2-class, 64-B rows): image slot ^= (row&3).
// gl_lds writes linearly (rule #21), so the swizzle is applied by
// inverse-permuting the per-lane GLOBAL source offset (lsw) and XORing the
// slot on every ds_read (qd ^ (lc&3)); same involution both sides.
// MODE 0: x @ [WqT|WkT|WvT|WgT]; q/k xpos -> bf16 hi/lo [h][s][d]; v -> transposed
//         bf16 hi/lo [h][d][s]; g -> fp32 [s][2048].
// MODE 1: y tiled planes @ WoT -> fp32, split-K=2 (kh=0 -> outC, kh=1 -> gbuf
//         partial, addp_kernel sums).
template<int MODE>
__global__ __launch_bounds__(256, 2)
void mfma_gemm(const ushort_t* __restrict__ Ahi, const ushort_t* __restrict__ Alo,
               const ushort_t* __restrict__ WT, const int* __restrict__ pos_ids,
               ushort_t* __restrict__ qhi, ushort_t* __restrict__ qlo,
               ushort_t* __restrict__ khi, ushort_t* __restrict__ klo,
               ushort_t* __restrict__ vThi, ushort_t* __restrict__ vTlo,
               float* __restrict__ gbuf, float* __restrict__ outC)
{
    __shared__ __align__(16) short sm[32768];   // 2 buffers x (4 planes x 8 KB)

    const int tid = threadIdx.x;
    const int w = tid >> 6, L = tid & 63;
    const int qd = L >> 4, lc = L & 15;
    const int lin = blockIdx.x;
    int n0, m0, kh = 0;
    if (MODE == 0) {   // XCD-stable n-groups: XCD (lin&7 heuristic) sees n-tiles 8j..8j+7
        n0 = (((lin & 7) << 3) + ((lin >> 3) & 7)) << 7;
        m0 = (lin >> 6) << 7;
    } else {
        n0 = (lin & 15) << 7;
        m0 = ((lin >> 4) & 15) << 7;
        kh = lin >> 8;
    }
    const size_t PL = (size_t)HIDD * HIDD;

    int sel, nn;
    const ushort_t *Bhi, *Blo;
    if (MODE == 0) {
        sel = n0 >> 11; nn = n0 & 2047;
        Bhi = WT + (size_t)sel * 2 * PL; Blo = Bhi + PL;
    } else {
        sel = -1; nn = n0;
        Bhi = WT; Blo = WT + PL;
    }

    // wave w stages plane w: 0:Ahi 1:Alo 2:Bhi 3:Blo
    const ushort_t* pbase = (w == 0) ? Ahi : (w == 1) ? Alo : (w == 2) ? Bhi : Blo;
    const int rt = ((w < 2) ? m0 : nn) >> 7;
    // inverse-swizzled per-lane source offset: lane L writes LDS row
    // r = t*16 + (L>>2), slot L&3; it must carry global slot (L&3)^(r&3).
    const int lsw = ((L >> 2) * 32) + (((L & 3) ^ ((L >> 2) & 3)) * 8);
    const ushort_t* tb0 = pbase + (size_t)rt * 64 * TILE_SH + lsw;

    const int wm = (w & 1) * 64, wn = (w >> 1) * 64;
    const int sx = (qd ^ (lc & 3)) * 8;        // swizzled slot on read
    int aoff[4], boff[4];
    #pragma unroll
    for (int i = 0; i < 4; i++) aoff[i] = (wm + i * 16 + lc) * 32 + sx;
    #pragma unroll
    for (int j = 0; j < 4; j++) boff[j] = (wn + j * 16 + lc) * 32 + sx;

    float4v acc[4][4];
    #pragma unroll
    for (int i = 0; i < 4; i++)
        #pragma unroll
        for (int j = 0; j < 4; j++)
            #pragma unroll
            for (int r = 0; r < 4; r++) acc[i][j][r] = 0.f;

    const int kt0 = (MODE == 1) ? kh * 32 : 0;
    const int kt1 = (MODE == 1) ? kt0 + 32 : 64;

    // prologue: stage first tile into buffer 0
    {
        const ushort_t* g = tb0 + (size_t)kt0 * TILE_SH;
        #pragma unroll
        for (int t = 0; t < 8; t++)
            gl_lds16(g + t * 512, sm + w * 4096 + t * 512);
        asm volatile("s_waitcnt vmcnt(0)" ::: "memory");
        __builtin_amdgcn_s_barrier();
        __builtin_amdgcn_sched_barrier(0);
    }

    int cur = 0;
    for (int kt = kt0; kt < kt1; kt++) {
        const short* cb = sm + (cur << 14);
        short* nb = sm + ((cur ^ 1) << 14);
        if (kt + 1 < kt1) {     // stage NEXT tile while computing current
            const ushort_t* g = tb0 + (size_t)(kt + 1) * TILE_SH;
            #pragma unroll
            for (int t = 0; t < 8; t++)
                gl_lds16(g + t * 512, nb + w * 4096 + t * 512);
        }

        short8 bhf[4], blf[4];
        #pragma unroll
        for (int j = 0; j < 4; j++) {
            bhf[j] = *(const short8*)(cb + 8192  + boff[j]);
            blf[j] = *(const short8*)(cb + 12288 + boff[j]);
        }
        #pragma unroll
        for (int i = 0; i < 4; i++) {
            const short8 ahf = *(const short8*)(cb + aoff[i]);
            const short8 alf = *(const short8*)(cb + 4096 + aoff[i]);
            #pragma unroll
            for (int j = 0; j < 4; j++) {
                acc[i][j] = __builtin_amdgcn_mfma_f32_16x16x32_bf16(ahf, bhf[j], acc[i][j], 0, 0, 0);
                acc[i][j] = __builtin_amdgcn_mfma_f32_16x16x32_bf16(alf, bhf[j], acc[i][j], 0, 0, 0);
                acc[i][j] = __builtin_amdgcn_mfma_f32_16x16x32_bf16(ahf, blf[j], acc[i][j], 0, 0, 0);
            }
        }

        asm volatile("s_waitcnt vmcnt(0)" ::: "memory");
        __builtin_amdgcn_s_barrier();
        __builtin_amdgcn_sched_barrier(0);
        cur ^= 1;
    }

    // ---- epilogue via LDS bounce; stores 16B/lane wave-contiguous.
    float* ob = (float*)sm;              // [32][132]
    const int half = w & 1;
    const int head = nn >> 7;

    // #pragma unroll is REQUIRED here (rule #20): without it, `i` is a runtime
    // index into acc[4][4] -> SROA fails -> the whole 64-float accumulator
    // lives in scratch for the ENTIRE kernel, including the K-loop MFMAs.
    // Evidence: VGPR_Count=64, WRITE_SIZE=3.85 GB/dispatch (scratch writebacks),
    // MfmaUtil 11%. Forcing unroll makes every acc index compile-time constant.
    #pragma unroll
    for (int i = 0; i < 4; i++) {
        #pragma unroll
        for (int j = 0; j < 4; j++)
            #pragma unroll
            for (int r = 0; r < 4; r++)
                ob[(half * 16 + qd * 4 + r) * 132 + wn + j * 16 + lc] = acc[i][j][r];
        __syncthreads();

        if (MODE == 1 || sel == 3) {
            float* dst = (MODE == 1) ? (kh ? gbuf : outC) : gbuf;
            #pragma unroll
            for (int p = 0; p < 4; p++) {
                const int row = p * 8 + (tid >> 5);
                const int c = (tid & 31) * 4;
                const int grow = m0 + (row >> 4) * 64 + i * 16 + (row & 15);
                const float4 vv = *(const float4*)&ob[row * 132 + c];
                *(float4*)&dst[(size_t)grow * HIDD + nn + c] = vv;
            }
        } else if (sel == 2) {
            const int d = tid >> 1, hs = tid & 1;
            const int sbase = m0 + hs * 64 + i * 16;
            short8 h0, h1, l0, l1;
            #pragma unroll
            for (int sp = 0; sp < 8; sp++) {
                float a = ob[(hs * 16 + sp) * 132 + d];
                ushort_t hb = f2bf(a);
                h0[sp] = (short)hb; l0[sp] = (short)f2bf(a - bf2f(hb));
                a = ob[(hs * 16 + 8 + sp) * 132 + d];
                hb = f2bf(a);
                h1[sp] = (short)hb; l1[sp] = (short)f2bf(a - bf2f(hb));
            }
            ushort_t* dh = vThi + ((size_t)head * HD + d) * S_LEN + sbase;
            ushort_t* dl = vTlo + ((size_t)head * HD + d) * S_LEN + sbase;
            *(short8*)dh = h0; *(short8*)(dh + 8) = h1;
            *(short8*)dl = l0; *(short8*)(dl + 8) = l1;
        } else {
            const float sgn = (sel == 0) ? 1.f : -1.f;
            ushort_t* dhb = (sel == 0) ? qhi : khi;
            ushort_t* dlb = (sel == 0) ? qlo : klo;
            #pragma unroll
            for (int p = 0; p < 2; p++) {
                const int row = p * 16 + (tid >> 4);
                const int c8 = (tid & 15) * 8;
                const int grow = m0 + (row >> 4) * 64 + i * 16 + (row & 15);
                const float pos = (float)pos_ids[grow];
                const float pe = sgn * pos * (1.f / 512.f);
                short8 hv, lv;
                #pragma unroll
                for (int pp = 0; pp < 4; pp++) {
                    const int d = c8 + pp * 2;
                    const float v0 = ob[row * 132 + d], v1 = ob[row * 132 + d + 1];
                    const float invf = exp2f(-(float)d * (13.28771238f / 128.f));
                    float s, c_; sincosf(pos * invf, &s, &c_);
                    const float scl = exp2f(log2f(((float)d + 51.2f) * (1.f / 179.2f)) * pe);
                    const float e0 = (v0 * c_ - v1 * s) * scl;
                    const float e1 = (v1 * c_ + v0 * s) * scl;
                    const ushort_t h0 = f2bf(e0), h1 = f2bf(e1);
                    hv[pp * 2] = (short)h0;  hv[pp * 2 + 1] = (short)h1;
                    lv[pp * 2] = (short)f2bf(e0 - bf2f(h0));
                    lv[pp * 2 + 1] = (short)f2bf(e1 - bf2f(h1));
                }
                *(short8*)&dhb[((size_t)head * S_LEN + grow) * HD + c8] = hv;
                *(short8*)&dlb[((size_t)head * S_LEN + grow) * HD + c8] = lv;
            }
        }
        __syncthreads();
    }
}

// Retention: MFMA QK^T -> decay -> P relayout -> MFMA PV -> groupnorm + silu gate
// -> y hi/lo TILED planes.  Block: (head, 64 q-rows), 4 waves.
#define KROW 136
#define VROW 40
#define KH_  0
#define KL_  (32 * KROW)
#define VH_  (2 * 32 * KROW)
#define VL_  (VH_ + 128 * VROW)
#define PH_  (VH_ + 2 * 128 * VROW)
#define PLO_ (PH_ + 64 * VROW)
#define YH_  8704
#define YL_  (YH_ + 64 * KROW)
__global__ __launch_bounds__(256, 2)
void retention2(const ushort_t* __restrict__ qhi, const ushort_t* __restrict__ qlo,
                const ushort_t* __restrict__ khi, const ushort_t* __restrict__ klo,
                const ushort_t* __restrict__ vThi, const ushort_t* __restrict__ vTlo,
                const float* __restrict__ gbuf, const float* __restrict__ gnw,
                const float* __restrict__ gnb,
                ushort_t* __restrict__ yhi, ushort_t* __restrict__ ylo)
{
    __shared__ __align__(16) short sm[26112];

    const int h = blockIdx.y;
    const int qb = (gridDim.x - 1) - blockIdx.x;
    const int r0 = qb * 64;
    const int tid = threadIdx.x;
    const int w = tid >> 6, L = tid & 63;
    const int qd = L >> 4, lc = L & 15;

    const float e = -3.4657359f + (float)h * ((-6.2383246f + 3.4657359f) / 15.f);
    const float lg2g = logf(1.f - expf(e)) * 1.44269504f;

    short8 qfh[4], qfl[4];
    {
        const size_t qb0 = ((size_t)h * S_LEN + r0 + w * 16 + lc) * HD + qd * 8;
        #pragma unroll
        for (int ks = 0; ks < 4; ks++) {
            qfh[ks] = *(const short8*)(qhi + qb0 + ks * 32);
            qfl[ks] = *(const short8*)(qlo + qb0 + ks * 32);
        }
    }

    float4v osum[2][4];
    #pragma unroll
    for (int mt = 0; mt < 2; mt++)
        #pragma unroll
        for (int j = 0; j < 4; j++)
            #pragma unroll
            for (int r = 0; r < 4; r++) osum[mt][j][r] = 0.f;

    const int qh_ = w >> 1, vh_ = w & 1;
    const int nch = (r0 + 64) / 32;

    for (int ch = 0; ch < nch; ch++) {
        const int kg0 = ch * 32;
        #pragma unroll
        for (int t = 0; t < 4; t++) {
            const int c = t * 256 + tid;
            const int p = c >> 9, r = (c >> 4) & 31, qq = c & 15;
            const ushort_t* src = (p ? klo : khi) + ((size_t)h * S_LEN + kg0 + r) * HD + qq * 8;
            *(short8*)(sm + (p ? KL_ : KH_) + r * KROW + qq * 8) = *(const short8*)src;
        }
        #pragma unroll
        for (int t = 0; t < 4; t++) {
            const int c = t * 256 + tid;
            const int p = c >> 9, r = (c >> 2) & 127, qq = c & 3;
            const ushort_t* src = (p ? vTlo : vThi) + ((size_t)h * HD + r) * S_LEN + kg0 + qq * 8;
            *(short8*)(sm + (p ? VL_ : VH_) + r * VROW + qq * 8) = *(const short8*)src;
        }
        __syncthreads();

        float4v sacc[2];
        #pragma unroll
        for (int j = 0; j < 2; j++)
            #pragma unroll
            for (int r = 0; r < 4; r++) sacc[j][r] = 0.f;
        #pragma unroll
        for (int ks = 0; ks < 4; ks++) {
            #pragma unroll
            for (int j = 0; j < 2; j++) {
                const short8 bh = *(const short8*)(sm + KH_ + (j * 16 + lc) * KROW + ks * 32 + qd * 8);
                const short8 bl = *(const short8*)(sm + KL_ + (j * 16 + lc) * KROW + ks * 32 + qd * 8);
                sacc[j] = __builtin_amdgcn_mfma_f32_16x16x32_bf16(qfh[ks], bh, sacc[j], 0, 0, 0);
                sacc[j] = __builtin_amdgcn_mfma_f32_16x16x32_bf16(qfl[ks], bh, sacc[j], 0, 0, 0);
                sacc[j] = __builtin_amdgcn_mfma_f32_16x16x32_bf16(qfh[ks], bl, sacc[j], 0, 0, 0);
            }
        }
        #pragma unroll
        for (int j = 0; j < 2; j++)
            #pragma unroll
            for (int r = 0; r < 4; r++) {
                const int dq = (r0 + w * 16 + qd * 4 + r) - (kg0 + j * 16 + lc);
                const float p = (dq >= 0) ? sacc[j][r] * exp2f(lg2g * (float)dq) : 0.f;
                const ushort_t hb = f2bf(p);
                const int off = (w * 16 + qd * 4 + r) * VROW + j * 16 + lc;
                sm[PH_ + off]  = (short)hb;
                sm[PLO_ + off] = (short)f2bf(p - bf2f(hb));
            }
        __syncthreads();

        #pragma unroll
        for (int mt = 0; mt < 2; mt++) {
            const short8 pfh = *(const short8*)(sm + PH_  + (qh_ * 32 + mt * 16 + lc) * VROW + qd * 8);
            const short8 pfl = *(const short8*)(sm + PLO_ + (qh_ * 32 + mt * 16 + lc) * VROW + qd * 8);
            #pragma unroll
            for (int j = 0; j < 4; j++) {
                const short8 vfh = *(const short8*)(sm + VH_ + (vh_ * 64 + j * 16 + lc) * VROW + qd * 8);
                const short8 vfl = *(const short8*)(sm + VL_ + (vh_ * 64 + j * 16 + lc) * VROW + qd * 8);
                osum[mt][j] = __builtin_amdgcn_mfma_f32_16x16x32_bf16(pfh, vfh, osum[mt][j], 0, 0, 0);
                osum[mt][j] = __builtin_amdgcn_mfma_f32_16x16x32_bf16(pfl, vfh, osum[mt][j], 0, 0, 0);
                osum[mt][j] = __builtin_amdgcn_mfma_f32_16x16x32_bf16(pfh, vfl, osum[mt][j], 0, 0, 0);
            }
        }
        __syncthreads();
    }

    float* fr = (float*)sm;
    #pragma unroll
    for (int mt = 0; mt < 2; mt++)
        #pragma unroll
        for (int r = 0; r < 4; r++) {
            float s1 = 0.f, s2 = 0.f;
            #pragma unroll
            for (int j = 0; j < 4; j++) { const float v = osum[mt][j][r]; s1 += v; s2 += v * v; }
            const int row = qh_ * 32 + mt * 16 + qd * 4 + r;
            fr[row * 32 + vh_ * 16 + lc] = s1;
            fr[2048 + row * 32 + vh_ * 16 + lc] = s2;
        }
    __syncthreads();
    if (tid < 64) {
        float s1 = 0.f, s2 = 0.f;
        #pragma unroll
        for (int t = 0; t < 32; t++) { s1 += fr[tid * 32 + t]; s2 += fr[2048 + tid * 32 + t]; }
        const float mean = s1 * (1.f / 128.f);
        const float var  = s2 * (1.f / 128.f) - mean * mean;
        fr[4096 + tid] = mean;
        fr[4160 + tid] = 1.f / sqrtf(var + 1e-5f);
    }
    __syncthreads();

    #pragma unroll
    for (int mt = 0; mt < 2; mt++)
        #pragma unroll
        for (int r = 0; r < 4; r++) {
            const int row = qh_ * 32 + mt * 16 + qd * 4 + r;
            const float mean = fr[4096 + row], inv = fr[4160 + row];
            const int grow = r0 + row;
            #pragma unroll
            for (int j = 0; j < 4; j++) {
                const int col = vh_ * 64 + j * 16 + lc;
                const float gv = gbuf[(size_t)grow * HIDD + h * HD + col];
                const float o = ((osum[mt][j][r] - mean) * inv * gnw[h * HD + col]
                                 + gnb[h * HD + col]) * silu_f(gv);
                const ushort_t hb = f2bf(o);
                sm[YH_ + row * KROW + col] = (short)hb;
                sm[YL_ + row * KROW + col] = (short)f2bf(o - bf2f(hb));
            }
        }
    __syncthreads();
    {
        // y -> TILED planes: row = r0+r_, col = h*128 + (tid&3)*32 + c8*8
        const int r_ = tid >> 2, cs = (tid & 3) * 32;
        const int grow = r0 + r_;
        const size_t tb = ((size_t)((grow >> 7) * 64 + h * 4 + (tid & 3))) * TILE_SH
                        + (grow & 127) * 32;
        #pragma unroll
        for (int c8 = 0; c8 < 4; c8++) {
            *(short8*)(yhi + tb + c8 * 8) = *(const short8*)(sm + YH_ + r_ * KROW + cs + c8 * 8);
            *(short8*)(ylo + tb + c8 * 8) = *(const short8*)(sm + YL_ + r_ * KROW + cs + c8 * 8);
        }
    }
}

extern "C" void kernel_launch(void* const* d_in, const int* in_sizes, int n_in,
                              void* d_out, int out_size, void* d_ws, size_t ws_size,
                              hipStream_t stream) {
    const float* x   = (const float*)d_in[0];
    const int*   pid = (const int*)d_in[1];
    const float* W[5] = {(const float*)d_in[2], (const float*)d_in[3], (const float*)d_in[4],
                         (const float*)d_in[5], (const float*)d_in[6]};
    const float* gnw = (const float*)d_in[7];
    const float* gnb = (const float*)d_in[8];
    float* out = (float*)d_out;
    (void)in_sizes; (void)n_in; (void)out_size; (void)ws_size;

    const size_t PL = (size_t)HIDD * HIDD;

    ushort_t* wt   = (ushort_t*)d_ws;          // 10 tiled planes = 80 MiB
    ushort_t* xhi  = wt + 10 * PL;             // tiled
    ushort_t* xlo  = xhi + PL;
    ushort_t* qhi_ = xlo + PL;                 // row-major [h][s][d]
    ushort_t* qlo_ = qhi_ + PL;
    ushort_t* khi_ = qlo_ + PL;
    ushort_t* klo_ = khi_ + PL;
    ushort_t* vThi = klo_ + PL;                // row-major [h][d][s]
    ushort_t* vTlo = vThi + PL;
    float*    gbuf = (float*)(vTlo + PL);      // row-major fp32
    ushort_t* yhi  = (ushort_t*)(gbuf + PL);   // tiled
    ushort_t* ylo  = yhi + PL;
    // MODE-1 split-K partial: reuse the x planes (dead after mfma_gemm<0>).
    float*    p1   = (float*)xhi;              // PL floats = 16 MiB = xhi+xlo

    split_kernel<<<(int)(PL / 4 / 256), 256, 0, stream>>>(x, xhi, xlo, (int)(PL / 4));
    for (int m = 0; m < 5; m++)
        split_transpose<<<dim3(32, 32), 256, 0, stream>>>(W[m], wt + (size_t)m * 2 * PL,
                                                          wt + (size_t)m * 2 * PL + PL);

    mfma_gemm<0><<<1024, 256, 0, stream>>>(xhi, xlo, wt, pid,
        qhi_, qlo_, khi_, klo_, vThi, vTlo, gbuf, nullptr);

    retention2<<<dim3(32, 16), 256, 0, stream>>>(qhi_, qlo_, khi_, klo_, vThi, vTlo,
        gbuf, gnw, gnb, yhi, ylo);

    mfma_gemm<1><<<512, 256, 0, stream>>>(yhi, ylo, wt + 8 * PL, pid,
        nullptr, nullptr, nullptr, nullptr, nullptr, nullptr, p1, out);

    addp_kernel<<<(int)(PL / 4 / 256), 256, 0, stream>>>(out, p1, (int)(PL / 4));
}